// Round 6
// baseline (135.548 us; speedup 1.0000x reference)
//
#include <hip/hip_runtime.h>
#include <math.h>

typedef float f32x2 __attribute__((ext_vector_type(2)));
typedef float f32x4 __attribute__((ext_vector_type(4)));

// Problem constants
#define B_     16
#define C_     32
#define D_     2
#define HW_    4096               // 64*64
#define NPIX   (B_ * D_ * HW_)    // 131072 pixels
#define NPAIRP 576                // padded pair slots: row c has rlen(c)=4*(c/4+1)
#define NROWSP 592                // + zero rows (margin in d_ws; not staged)

// ---------------------------------------------------------------------------
// Prep (validated R2-R4): fold weight [O,C,C] into padded symmetric pair table
//   wpad[kp][o]. Row c starts at kpbase(c)=4*(c+2a(a-1)+ab), a=c>>2, b=c&3.
//   Slot j<=c: W[o,c,j]+W[o,j,c] (diag once); pad slots = 0.
// ---------------------------------------------------------------------------
__global__ void prep_wsym(const float* __restrict__ w, float* __restrict__ wpad) {
    int idx = blockIdx.x * blockDim.x + threadIdx.x;
    const int total1 = 32 * 32 * 32;
    const int totalz = (NROWSP - NPAIRP) * 32;
    if (idx < total1) {
        int o = idx & 31;
        int j = (idx >> 5) & 31;
        int c = idx >> 10;
        int a = c >> 2, b = c & 3;
        int rlen = (a + 1) << 2;
        if (j >= rlen) return;
        int kb = 4 * (c + 2 * a * (a - 1) + a * b);
        float v = 0.0f;
        if (j <= c) {
            const float* wo = w + o * (C_ * C_);
            v = (j == c) ? wo[c * C_ + c] : (wo[c * C_ + j] + wo[j * C_ + c]);
        }
        wpad[(kb + j) * 32 + o] = v;
    } else if (idx < total1 + totalz) {
        wpad[NPAIRP * 32 + (idx - total1)] = 0.0f;
    }
}

// ---------------------------------------------------------------------------
// Main kernel. Block = 512 threads = 8 waves over 256 pixels:
//   wave (wv, pg): wv = o-half (16 outputs), pg = pixel quarter (64 pixels).
// Grid = 512 blocks -> 2 blocks/CU resident, 16 waves/CU = 4 waves/SIMD.
//
// Weights live in LDS (73,728 B staged once per block): inner-loop reads are
// wave-uniform ds_read (bank broadcast, conflict-free), so lgkmcnt carries
// ONLY in-order DS traffic -> compiler emits counted waits and pipelines.
// No scalar weight loads -> the per-CU scalar unit (R3/R4's 66% cap) is idle.
//
// Trig: e-side cached in registers per eb-block (4 sincos); c-side recomputed
// per c-iter from a software-prefetched global x load (L1/L2-hot, 32KB/block).
// Accumulate with f32x2 packed FMA (v_pk_fma_f32 if full-rate on CDNA4).
// ---------------------------------------------------------------------------
#define TPB 512

__global__ __launch_bounds__(TPB, 4) void bilinear_kernel(
    const float* __restrict__ x,
    const float* __restrict__ wpad,
    const float* __restrict__ bias,
    float* __restrict__ out)
{
    __shared__ float wlds[NPAIRP * 32];   // 73,728 B

    // ---- stage weight table: 512 threads x 9 float4 = 18,432 floats ----
    {
        const f32x4* src = (const f32x4*)wpad;
        f32x4* dst = (f32x4*)wlds;
        #pragma unroll
        for (int i = 0; i < 9; ++i) {
            int idx = i * TPB + threadIdx.x;
            dst[idx] = src[idx];
        }
    }
    __syncthreads();

    const int l   = threadIdx.x & 63;
    const int wv  = (threadIdx.x >> 6) & 1;      // o-half
    const int pg  = threadIdx.x >> 7;            // pixel quarter (0..3)
    const int pix = (pg << 6) + l;
    const int P0  = blockIdx.x * 256;
    const int b   = P0 >> 13;
    const int d   = (P0 >> 12) & 1;
    const int hw0 = P0 & 4095;                   // 256-aligned, stays in (b,d)
    const int base = b * (C_ * D_ * HW_) + d * HW_ + hw0 + pix;  // +c*8192 per ch

    const float* __restrict__ xp = x + base;

    f32x2 ar[8], ai[8];
    #pragma unroll
    for (int j = 0; j < 8; ++j) { ar[j] = (f32x2)0.0f; ai[j] = (f32x2)0.0f; }

    const float* __restrict__ wl = wlds + wv * 16;   // our o-half of each 32-float row

    #pragma unroll 1
    for (int eb = 0; eb < 8; ++eb) {
        const int e0 = eb << 2;
        float ce[4], se[4];
        #pragma unroll
        for (int j = 0; j < 4; ++j) {
            float xe = xp[(e0 + j) * (D_ * HW_)];
            __sincosf(xe, &se[j], &ce[j]);
        }
        int kpb = 8 * eb * (eb + 1);       // kpbase(4*eb)
        float xv = xp[e0 * (D_ * HW_)];    // prefetch first c's angle
        #pragma unroll 1
        for (int c = e0; c < C_; ++c) {
            float xnext = (c + 1 < C_) ? xp[(c + 1) * (D_ * HW_)] : 0.0f;
            float cv, sv;
            __sincosf(xv, &sv, &cv);
            const float* wr = wl + (kpb + e0) * 32;
            #pragma unroll
            for (int p = 0; p < 4; ++p) {
                float ur = fmaf(cv, ce[p], -(sv * se[p]));
                float ui = fmaf(cv, se[p],   sv * ce[p]);
                f32x2 ur2 = {ur, ur}, ui2 = {ui, ui};
                const f32x2* __restrict__ w2 = (const f32x2*)(wr + p * 32);
                #pragma unroll
                for (int j = 0; j < 8; ++j) {
                    ar[j] = __builtin_elementwise_fma(w2[j], ur2, ar[j]);
                    ai[j] = __builtin_elementwise_fma(w2[j], ui2, ai[j]);
                }
            }
            kpb += ((c >> 2) + 1) << 2;    // += rowlen(c)
            xv = xnext;
        }
    }

    // ---- epilogue: angle + bias, coalesced stores ----
    #pragma unroll
    for (int j = 0; j < 8; ++j) {
        #pragma unroll
        for (int k = 0; k < 2; ++k) {
            const int o = wv * 16 + 2 * j + k;
            out[base + o * (D_ * HW_)] = atan2f(ai[j][k], ar[j][k]) + bias[o];
        }
    }
}

// ---------------------------------------------------------------------------
extern "C" void kernel_launch(void* const* d_in, const int* in_sizes, int n_in,
                              void* d_out, int out_size, void* d_ws, size_t ws_size,
                              hipStream_t stream) {
    const float* x    = (const float*)d_in[0];
    const float* w    = (const float*)d_in[1];
    const float* bias = (const float*)d_in[2];
    float* out        = (float*)d_out;
    float* wpad       = (float*)d_ws;   // needs NROWSP*32*4 = 75,776 B

    {
        int n = 32 * 32 * 32 + (NROWSP - NPAIRP) * 32;
        int tpb = 256;
        prep_wsym<<<(n + tpb - 1) / tpb, tpb, 0, stream>>>(w, wpad);
    }
    {
        int grid = NPIX / 256;   // 512 blocks, 8 waves each -> 2 blocks/CU
        bilinear_kernel<<<grid, TPB, 0, stream>>>(x, wpad, bias, out);
    }
}